// Round 3
// baseline (2895.114 us; speedup 1.0000x reference)
//
#include <hip/hip_runtime.h>

// out[n] = sum_{e: dst_e = n} (x2[src_e] - x2[dst_e]),  x2 = x @ W   (bias cancels)
// Stage 1: zero out. Stage 2: GEMM x@W -> ws. Stage 3: edge-parallel atomic scatter.

#define C_DIM 128

__global__ __launch_bounds__(256) void zero_f4(float4* p, int n4) {
    int i = blockIdx.x * 256 + threadIdx.x;
    if (i < n4) p[i] = make_float4(0.f, 0.f, 0.f, 0.f);
}

// x: [nrows,128] fp32, W: [128,128] fp32, x2: [nrows,128] fp32
// Block = 256 threads, tile = 64 rows x 128 cols, per-thread 4x8 accumulators.
// W (64KB) staged once per block in LDS; x tile stored k-major (xl[k][r]) so the
// inner loop reads are 1x ds_read_b128 (x, 4 consecutive rows) + 2x ds_read_b128 (W).
__global__ __launch_bounds__(256) void gemm128(const float* __restrict__ x,
                                               const float* __restrict__ W,
                                               float* __restrict__ x2, int nrows) {
    __shared__ float Wl[128 * 128];   // 64 KB
    __shared__ float xl[128][64];     // 32 KB, k-major

    for (int i = threadIdx.x; i < 128 * 128 / 4; i += 256)
        ((float4*)Wl)[i] = ((const float4*)W)[i];

    const int tx = threadIdx.x & 15;   // 16 col groups * 8 cols
    const int ty = threadIdx.x >> 4;   // 16 row groups * 4 rows

    for (int tile = blockIdx.x; tile * 64 < nrows; tile += gridDim.x) {
        const int row0 = tile * 64;
        __syncthreads();   // protect xl from previous iteration readers
        for (int i = threadIdx.x; i < 64 * 32; i += 256) {
            int r = i >> 5;          // row within tile (32 float4 per row)
            int k4 = i & 31;         // float4 index along k
            int gr = row0 + r;
            float4 v = make_float4(0.f, 0.f, 0.f, 0.f);
            if (gr < nrows) v = ((const float4*)(x + (size_t)gr * C_DIM))[k4];
            xl[k4 * 4 + 0][r] = v.x;
            xl[k4 * 4 + 1][r] = v.y;
            xl[k4 * 4 + 2][r] = v.z;
            xl[k4 * 4 + 3][r] = v.w;
        }
        __syncthreads();

        float acc[4][8];
#pragma unroll
        for (int i = 0; i < 4; i++)
#pragma unroll
            for (int j = 0; j < 8; j++) acc[i][j] = 0.f;

#pragma unroll 8
        for (int k = 0; k < 128; k++) {
            const float4 xv = *(const float4*)&xl[k][ty * 4];
            const float4 w0 = *(const float4*)&Wl[k * 128 + tx * 8];
            const float4 w1 = *(const float4*)&Wl[k * 128 + tx * 8 + 4];
            const float xs[4] = {xv.x, xv.y, xv.z, xv.w};
            const float ws[8] = {w0.x, w0.y, w0.z, w0.w, w1.x, w1.y, w1.z, w1.w};
#pragma unroll
            for (int i = 0; i < 4; i++)
#pragma unroll
                for (int j = 0; j < 8; j++)
                    acc[i][j] = fmaf(xs[i], ws[j], acc[i][j]);
        }

#pragma unroll
        for (int i = 0; i < 4; i++) {
            int gr = row0 + ty * 4 + i;
            if (gr < nrows) {
                float4* o = (float4*)(x2 + (size_t)gr * C_DIM + tx * 8);
                o[0] = make_float4(acc[i][0], acc[i][1], acc[i][2], acc[i][3]);
                o[1] = make_float4(acc[i][4], acc[i][5], acc[i][6], acc[i][7]);
            }
        }
    }
}

// One thread per (edge, 4-channel chunk): 32 threads cover an edge's 128 channels.
// ei[e] = dst (aggregation target), ei[ne+e] = src (message source).
__global__ __launch_bounds__(256) void scatter_edges(const int* __restrict__ ei,
                                                     const float* __restrict__ x2,
                                                     float* __restrict__ out,
                                                     int ne, int nn) {
    long long g = (long long)blockIdx.x * 256 + threadIdx.x;
    long long total = (long long)ne * 32;
    if (g >= total) return;
    int e = (int)(g >> 5);
    int q = (int)(g & 31);
    int dst = ei[e];
    int src = ei[ne + e];
    if ((unsigned)dst >= (unsigned)nn || (unsigned)src >= (unsigned)nn) return;  // OOB guard
    float4 vs = ((const float4*)(x2 + (size_t)src * C_DIM))[q];
    float4 vd = ((const float4*)(x2 + (size_t)dst * C_DIM))[q];
    float* o = out + (size_t)dst * C_DIM + q * 4;
    atomicAdd(o + 0, vs.x - vd.x);
    atomicAdd(o + 1, vs.y - vd.y);
    atomicAdd(o + 2, vs.z - vd.z);
    atomicAdd(o + 3, vs.w - vd.w);
}

extern "C" void kernel_launch(void* const* d_in, const int* in_sizes, int n_in,
                              void* d_out, int out_size, void* d_ws, size_t ws_size,
                              hipStream_t stream) {
    const float* x = (const float*)d_in[0];
    const int* ei = (const int*)d_in[1];
    const float* W = (const float*)d_in[2];
    // d_in[3] (bias) is provably unused: it cancels in out = A@x2 - x2*deg.
    float* out = (float*)d_out;
    float* x2 = (float*)d_ws;   // needs n*128*4 = 51.2 MB of workspace

    int n = in_sizes[0] / C_DIM;    // 100000
    int ne = in_sizes[1] / 2;       // 1600000

    int n4 = out_size / 4;
    zero_f4<<<(n4 + 255) / 256, 256, 0, stream>>>((float4*)out, n4);

    int ntiles = (n + 63) / 64;
    gemm128<<<ntiles, 256, 0, stream>>>(x, W, x2, n);

    long long total = (long long)ne * 32;
    int blocks = (int)((total + 255) / 256);
    scatter_edges<<<blocks, 256, 0, stream>>>(ei, x2, out, ne, n);
}

// Round 4
// 729.664 us; speedup vs baseline: 3.9677x; 3.9677x over previous
//
#include <hip/hip_runtime.h>

// out[n] = sum_{e: dst_e = n} (x2[src_e] - x2[dst_e]),  x2 = x @ W   (bias cancels)
// Pipeline: GEMM x@W -> x2 (ws); build CSR by dst (count/scan/fill, int atomics only);
// gather: one wave per node, out written exactly once (no zeroing, no fp32 atomics).

#define C_DIM 128

// ---------------- GEMM (unchanged from baseline) ----------------
__global__ __launch_bounds__(256) void gemm128(const float* __restrict__ x,
                                               const float* __restrict__ W,
                                               float* __restrict__ x2, int nrows) {
    __shared__ float Wl[128 * 128];   // 64 KB
    __shared__ float xl[128][64];     // 32 KB, k-major

    for (int i = threadIdx.x; i < 128 * 128 / 4; i += 256)
        ((float4*)Wl)[i] = ((const float4*)W)[i];

    const int tx = threadIdx.x & 15;   // 16 col groups * 8 cols
    const int ty = threadIdx.x >> 4;   // 16 row groups * 4 rows

    for (int tile = blockIdx.x; tile * 64 < nrows; tile += gridDim.x) {
        const int row0 = tile * 64;
        __syncthreads();
        for (int i = threadIdx.x; i < 64 * 32; i += 256) {
            int r = i >> 5;
            int k4 = i & 31;
            int gr = row0 + r;
            float4 v = make_float4(0.f, 0.f, 0.f, 0.f);
            if (gr < nrows) v = ((const float4*)(x + (size_t)gr * C_DIM))[k4];
            xl[k4 * 4 + 0][r] = v.x;
            xl[k4 * 4 + 1][r] = v.y;
            xl[k4 * 4 + 2][r] = v.z;
            xl[k4 * 4 + 3][r] = v.w;
        }
        __syncthreads();

        float acc[4][8];
#pragma unroll
        for (int i = 0; i < 4; i++)
#pragma unroll
            for (int j = 0; j < 8; j++) acc[i][j] = 0.f;

#pragma unroll 8
        for (int k = 0; k < 128; k++) {
            const float4 xv = *(const float4*)&xl[k][ty * 4];
            const float4 w0 = *(const float4*)&Wl[k * 128 + tx * 8];
            const float4 w1 = *(const float4*)&Wl[k * 128 + tx * 8 + 4];
            const float xs[4] = {xv.x, xv.y, xv.z, xv.w};
            const float ws[8] = {w0.x, w0.y, w0.z, w0.w, w1.x, w1.y, w1.z, w1.w};
#pragma unroll
            for (int i = 0; i < 4; i++)
#pragma unroll
                for (int j = 0; j < 8; j++)
                    acc[i][j] = fmaf(xs[i], ws[j], acc[i][j]);
        }

#pragma unroll
        for (int i = 0; i < 4; i++) {
            int gr = row0 + ty * 4 + i;
            if (gr < nrows) {
                float4* o = (float4*)(x2 + (size_t)gr * C_DIM + tx * 8);
                o[0] = make_float4(acc[i][0], acc[i][1], acc[i][2], acc[i][3]);
                o[1] = make_float4(acc[i][4], acc[i][5], acc[i][6], acc[i][7]);
            }
        }
    }
}

// ---------------- CSR build ----------------
__global__ __launch_bounds__(256) void zero_ints(int* p, int n) {
    int i = blockIdx.x * 256 + threadIdx.x;
    if (i < n) p[i] = 0;
}

__global__ __launch_bounds__(256) void count_deg(const int* __restrict__ ei,
                                                 int* __restrict__ cnt, int ne, int nn) {
    int e = blockIdx.x * 256 + threadIdx.x;
    if (e >= ne) return;
    int dst = ei[e];
    if ((unsigned)dst < (unsigned)nn) atomicAdd(&cnt[dst], 1);
}

// Single-block exclusive scan over cnt[n] -> start[n]; also copies to next[n].
__global__ __launch_bounds__(1024) void scan_start(const int* __restrict__ cnt,
                                                   int* __restrict__ start,
                                                   int* __restrict__ next, int n) {
    __shared__ int sums[1024];
    const int chunk = (n + 1023) / 1024;
    const int lo = threadIdx.x * chunk;
    const int hi = min(lo + chunk, n);
    int s = 0;
    for (int i = lo; i < hi; i++) s += cnt[i];
    sums[threadIdx.x] = s;
    __syncthreads();
    // inclusive Hillis-Steele scan in LDS
    for (int off = 1; off < 1024; off <<= 1) {
        int t = (threadIdx.x >= off) ? sums[threadIdx.x - off] : 0;
        __syncthreads();
        sums[threadIdx.x] += t;
        __syncthreads();
    }
    int running = sums[threadIdx.x] - s;   // exclusive offset for this chunk
    for (int i = lo; i < hi; i++) {
        start[i] = running;
        next[i] = running;
        running += cnt[i];
    }
}

__global__ __launch_bounds__(256) void fill_csr(const int* __restrict__ ei,
                                                int* __restrict__ next,
                                                int* __restrict__ csr, int ne, int nn) {
    int e = blockIdx.x * 256 + threadIdx.x;
    if (e >= ne) return;
    int dst = ei[e];
    int src = ei[ne + e];
    if ((unsigned)dst >= (unsigned)nn || (unsigned)src >= (unsigned)nn) return;
    int slot = atomicAdd(&next[dst], 1);
    csr[slot] = src;
}

// ---------------- gather: one wave (64 lanes) per destination node ----------------
// lane l owns channels [2l, 2l+1] (float2) -> one 512B coalesced read per edge.
__global__ __launch_bounds__(256) void gather_out(const int* __restrict__ csr,
                                                  const int* __restrict__ start,
                                                  const int* __restrict__ cnt,
                                                  const float* __restrict__ x2,
                                                  float* __restrict__ out, int nn) {
    int wave = (int)((blockIdx.x * 256 + threadIdx.x) >> 6);
    int lane = threadIdx.x & 63;
    if (wave >= nn) return;
    const int node = wave;
    const int s0 = start[node];
    const int dg = cnt[node];
    const float2* __restrict__ base = (const float2*)x2;

    float2 acc0 = make_float2(0.f, 0.f);
    float2 acc1 = make_float2(0.f, 0.f);
    int e = 0;
    for (; e + 2 <= dg; e += 2) {
        int s1 = csr[s0 + e];
        int s2 = csr[s0 + e + 1];
        float2 v1 = base[(size_t)s1 * 64 + lane];
        float2 v2 = base[(size_t)s2 * 64 + lane];
        acc0.x += v1.x; acc0.y += v1.y;
        acc1.x += v2.x; acc1.y += v2.y;
    }
    if (e < dg) {
        int s1 = csr[s0 + e];
        float2 v1 = base[(size_t)s1 * 64 + lane];
        acc0.x += v1.x; acc0.y += v1.y;
    }
    float2 self = base[(size_t)node * 64 + lane];
    float d = (float)dg;
    float2 o;
    o.x = acc0.x + acc1.x - d * self.x;
    o.y = acc0.y + acc1.y - d * self.y;
    ((float2*)out)[(size_t)node * 64 + lane] = o;
}

extern "C" void kernel_launch(void* const* d_in, const int* in_sizes, int n_in,
                              void* d_out, int out_size, void* d_ws, size_t ws_size,
                              hipStream_t stream) {
    const float* x = (const float*)d_in[0];
    const int* ei = (const int*)d_in[1];
    const float* W = (const float*)d_in[2];
    // d_in[3] (bias) provably unused: cancels in out = A@x2 - x2*deg.
    float* out = (float*)d_out;

    const int n = in_sizes[0] / C_DIM;     // 100000
    const int ne = in_sizes[1] / 2;        // 1600000

    // workspace layout (bytes): x2[n*128 f32] | cnt[n] | start[n] | next[n] | csr[ne]
    char* ws = (char*)d_ws;
    float* x2 = (float*)ws;                     ws += (size_t)n * C_DIM * sizeof(float);
    int* cnt = (int*)ws;                        ws += (size_t)n * sizeof(int);
    int* start = (int*)ws;                      ws += (size_t)n * sizeof(int);
    int* next = (int*)ws;                       ws += (size_t)n * sizeof(int);
    int* csr = (int*)ws;

    zero_ints<<<(n + 255) / 256, 256, 0, stream>>>(cnt, n);

    int ntiles = (n + 63) / 64;
    gemm128<<<ntiles, 256, 0, stream>>>(x, W, x2, n);

    int eblocks = (ne + 255) / 256;
    count_deg<<<eblocks, 256, 0, stream>>>(ei, cnt, ne, n);
    scan_start<<<1, 1024, 0, stream>>>(cnt, start, next, n);
    fill_csr<<<eblocks, 256, 0, stream>>>(ei, next, csr, ne, n);

    int gblocks = (n + 3) / 4;   // 4 waves per block, 1 node per wave
    gather_out<<<gblocks, 256, 0, stream>>>(csr, start, cnt, x2, out, n);
}

// Round 7
// 514.086 us; speedup vs baseline: 5.6316x; 1.4193x over previous
//
#include <hip/hip_runtime.h>

// out[n] = sum_{e: dst_e = n} (x2[src_e] - x2[dst_e]),  x2 = x @ W   (bias cancels)
// Pipeline: GEMM x@W -> x2 (ws); build CSR by dst (count / 3-phase scan / fill);
// gather: one wave per node, out written exactly once (no fp32 atomics).

#define C_DIM 128

// ---------------- GEMM (unchanged) ----------------
__global__ __launch_bounds__(256) void gemm128(const float* __restrict__ x,
                                               const float* __restrict__ W,
                                               float* __restrict__ x2, int nrows) {
    __shared__ float Wl[128 * 128];   // 64 KB
    __shared__ float xl[128][64];     // 32 KB, k-major

    for (int i = threadIdx.x; i < 128 * 128 / 4; i += 256)
        ((float4*)Wl)[i] = ((const float4*)W)[i];

    const int tx = threadIdx.x & 15;
    const int ty = threadIdx.x >> 4;

    for (int tile = blockIdx.x; tile * 64 < nrows; tile += gridDim.x) {
        const int row0 = tile * 64;
        __syncthreads();
        for (int i = threadIdx.x; i < 64 * 32; i += 256) {
            int r = i >> 5;
            int k4 = i & 31;
            int gr = row0 + r;
            float4 v = make_float4(0.f, 0.f, 0.f, 0.f);
            if (gr < nrows) v = ((const float4*)(x + (size_t)gr * C_DIM))[k4];
            xl[k4 * 4 + 0][r] = v.x;
            xl[k4 * 4 + 1][r] = v.y;
            xl[k4 * 4 + 2][r] = v.z;
            xl[k4 * 4 + 3][r] = v.w;
        }
        __syncthreads();

        float acc[4][8];
#pragma unroll
        for (int i = 0; i < 4; i++)
#pragma unroll
            for (int j = 0; j < 8; j++) acc[i][j] = 0.f;

#pragma unroll 8
        for (int k = 0; k < 128; k++) {
            const float4 xv = *(const float4*)&xl[k][ty * 4];
            const float4 w0 = *(const float4*)&Wl[k * 128 + tx * 8];
            const float4 w1 = *(const float4*)&Wl[k * 128 + tx * 8 + 4];
            const float xs[4] = {xv.x, xv.y, xv.z, xv.w};
            const float ws[8] = {w0.x, w0.y, w0.z, w0.w, w1.x, w1.y, w1.z, w1.w};
#pragma unroll
            for (int i = 0; i < 4; i++)
#pragma unroll
                for (int j = 0; j < 8; j++)
                    acc[i][j] = fmaf(xs[i], ws[j], acc[i][j]);
        }

#pragma unroll
        for (int i = 0; i < 4; i++) {
            int gr = row0 + ty * 4 + i;
            if (gr < nrows) {
                float4* o = (float4*)(x2 + (size_t)gr * C_DIM + tx * 8);
                o[0] = make_float4(acc[i][0], acc[i][1], acc[i][2], acc[i][3]);
                o[1] = make_float4(acc[i][4], acc[i][5], acc[i][6], acc[i][7]);
            }
        }
    }
}

// ---------------- CSR build ----------------
__global__ __launch_bounds__(256) void zero_ints(int* p, int n) {
    int i = blockIdx.x * 256 + threadIdx.x;
    if (i < n) p[i] = 0;
}

__global__ __launch_bounds__(256) void count_deg(const int* __restrict__ ei,
                                                 int* __restrict__ cnt, int ne, int nn) {
    int e = blockIdx.x * 256 + threadIdx.x;
    if (e >= ne) return;
    int dst = ei[e];
    if ((unsigned)dst < (unsigned)nn) atomicAdd(&cnt[dst], 1);
}

// ---- 3-phase device-wide exclusive scan over cnt[n] (tile = 1024 = 256 thr x int4) ----
__global__ __launch_bounds__(256) void scan_partials(const int* __restrict__ cnt,
                                                     int* __restrict__ bsum, int n) {
    __shared__ int red[256];
    int i = blockIdx.x * 1024 + threadIdx.x * 4;
    int s = 0;
    if (i + 3 < n) {
        int4 v = *(const int4*)(cnt + i);
        s = v.x + v.y + v.z + v.w;
    } else {
        for (int j = i; j < n && j < i + 4; j++) s += cnt[j];
    }
    red[threadIdx.x] = s;
    __syncthreads();
    for (int off = 128; off > 0; off >>= 1) {
        if (threadIdx.x < off) red[threadIdx.x] += red[threadIdx.x + off];
        __syncthreads();
    }
    if (threadIdx.x == 0) bsum[blockIdx.x] = red[0];
}

// Exclusive scan over nb (<=1024) block sums, in place.
__global__ __launch_bounds__(1024) void scan_bsums(int* __restrict__ bsum, int nb) {
    __shared__ int s[1024];
    int v = (threadIdx.x < nb) ? bsum[threadIdx.x] : 0;
    s[threadIdx.x] = v;
    __syncthreads();
    for (int off = 1; off < 1024; off <<= 1) {
        int t = (threadIdx.x >= off) ? s[threadIdx.x - off] : 0;
        __syncthreads();
        s[threadIdx.x] += t;
        __syncthreads();
    }
    if (threadIdx.x < nb) bsum[threadIdx.x] = s[threadIdx.x] - v;  // exclusive
}

__global__ __launch_bounds__(256) void scan_apply(const int* __restrict__ cnt,
                                                  const int* __restrict__ bsum,
                                                  int* __restrict__ start,
                                                  int* __restrict__ next, int n) {
    __shared__ int s[256];
    int i = blockIdx.x * 1024 + threadIdx.x * 4;
    int4 v = make_int4(0, 0, 0, 0);
    if (i + 3 < n) {
        v = *(const int4*)(cnt + i);
    } else {
        if (i + 0 < n) v.x = cnt[i + 0];
        if (i + 1 < n) v.y = cnt[i + 1];
        if (i + 2 < n) v.z = cnt[i + 2];
        if (i + 3 < n) v.w = cnt[i + 3];
    }
    int tsum = v.x + v.y + v.z + v.w;
    s[threadIdx.x] = tsum;
    __syncthreads();
    for (int off = 1; off < 256; off <<= 1) {
        int t = (threadIdx.x >= off) ? s[threadIdx.x - off] : 0;
        __syncthreads();
        s[threadIdx.x] += t;
        __syncthreads();
    }
    int r0 = s[threadIdx.x] - tsum + bsum[blockIdx.x];
    int r1 = r0 + v.x, r2 = r1 + v.y, r3 = r2 + v.z;
    if (i + 3 < n) {
        *(int4*)(start + i) = make_int4(r0, r1, r2, r3);
        *(int4*)(next + i) = make_int4(r0, r1, r2, r3);
    } else {
        int rr[4] = {r0, r1, r2, r3};
        for (int j = 0; j < 4 && i + j < n; j++) {
            start[i + j] = rr[j];
            next[i + j] = rr[j];
        }
    }
}

__global__ __launch_bounds__(256) void fill_csr(const int* __restrict__ ei,
                                                int* __restrict__ next,
                                                int* __restrict__ csr, int ne, int nn) {
    int e = blockIdx.x * 256 + threadIdx.x;
    if (e >= ne) return;
    int dst = ei[e];
    int src = ei[ne + e];
    if ((unsigned)dst >= (unsigned)nn || (unsigned)src >= (unsigned)nn) return;
    int slot = atomicAdd(&next[dst], 1);
    csr[slot] = src;
}

// ---------------- gather: one wave (64 lanes) per destination node ----------------
__global__ __launch_bounds__(256) void gather_out(const int* __restrict__ csr,
                                                  const int* __restrict__ start,
                                                  const int* __restrict__ cnt,
                                                  const float* __restrict__ x2,
                                                  float* __restrict__ out, int nn) {
    int wave = (int)((blockIdx.x * 256 + threadIdx.x) >> 6);
    int lane = threadIdx.x & 63;
    if (wave >= nn) return;
    const int node = wave;
    const int s0 = start[node];
    const int dg = cnt[node];
    const float2* __restrict__ base = (const float2*)x2;

    float2 acc0 = make_float2(0.f, 0.f);
    float2 acc1 = make_float2(0.f, 0.f);
    int e = 0;
    for (; e + 2 <= dg; e += 2) {
        int s1 = csr[s0 + e];
        int s2 = csr[s0 + e + 1];
        float2 v1 = base[(size_t)s1 * 64 + lane];
        float2 v2 = base[(size_t)s2 * 64 + lane];
        acc0.x += v1.x; acc0.y += v1.y;
        acc1.x += v2.x; acc1.y += v2.y;
    }
    if (e < dg) {
        int s1 = csr[s0 + e];
        float2 v1 = base[(size_t)s1 * 64 + lane];
        acc0.x += v1.x; acc0.y += v1.y;
    }
    float2 self = base[(size_t)node * 64 + lane];
    float d = (float)dg;
    float2 o;
    o.x = acc0.x + acc1.x - d * self.x;
    o.y = acc0.y + acc1.y - d * self.y;
    ((float2*)out)[(size_t)node * 64 + lane] = o;
}

extern "C" void kernel_launch(void* const* d_in, const int* in_sizes, int n_in,
                              void* d_out, int out_size, void* d_ws, size_t ws_size,
                              hipStream_t stream) {
    const float* x = (const float*)d_in[0];
    const int* ei = (const int*)d_in[1];
    const float* W = (const float*)d_in[2];
    // d_in[3] (bias) provably unused: cancels in out = A@x2 - x2*deg.
    float* out = (float*)d_out;

    const int n = in_sizes[0] / C_DIM;     // 100000
    const int ne = in_sizes[1] / 2;        // 1600000

    // ws layout: x2[n*128 f32] | cnt[n] | start[n] | next[n] | bsum[nb] | csr[ne]
    const int nb = (n + 1023) / 1024;      // scan tiles (98 for n=100000, must be <=1024)
    char* ws = (char*)d_ws;
    float* x2 = (float*)ws;                 ws += (size_t)n * C_DIM * sizeof(float);
    int* cnt = (int*)ws;                    ws += (size_t)n * sizeof(int);
    int* start = (int*)ws;                  ws += (size_t)n * sizeof(int);
    int* next = (int*)ws;                   ws += (size_t)n * sizeof(int);
    int* bsum = (int*)ws;                   ws += (size_t)((nb + 3) & ~3) * sizeof(int);
    int* csr = (int*)ws;

    zero_ints<<<(n + 255) / 256, 256, 0, stream>>>(cnt, n);

    int ntiles = (n + 63) / 64;
    gemm128<<<ntiles, 256, 0, stream>>>(x, W, x2, n);

    int eblocks = (ne + 255) / 256;
    count_deg<<<eblocks, 256, 0, stream>>>(ei, cnt, ne, n);

    scan_partials<<<nb, 256, 0, stream>>>(cnt, bsum, n);
    scan_bsums<<<1, 1024, 0, stream>>>(bsum, nb);
    scan_apply<<<nb, 256, 0, stream>>>(cnt, bsum, start, next, n);

    fill_csr<<<eblocks, 256, 0, stream>>>(ei, next, csr, ne, n);

    int gblocks = (n + 3) / 4;   // 4 waves per block, 1 node per wave
    gather_out<<<gblocks, 256, 0, stream>>>(csr, start, cnt, x2, out, n);
}

// Round 8
// 400.018 us; speedup vs baseline: 7.2375x; 1.2852x over previous
//
#include <hip/hip_runtime.h>

// out[n] = sum_{e: dst_e = n} (x2[src_e] - x2[dst_e]),  x2 = x @ W   (bias cancels)
// Pipeline: MFMA bf16 GEMM x@W -> x2f (fp32) + x2b (bf16); CSR build (count/scan/fill);
// gather: one wave per node; src-sum from bf16 x2, self term from fp32 x2.

#define C_DIM 128

typedef __attribute__((ext_vector_type(8))) short bf16x8;
typedef __attribute__((ext_vector_type(4))) float f32x4;

__device__ __forceinline__ ushort f2b(float f) {   // fp32 -> bf16 RNE
    uint u = __float_as_uint(f);
    u = (u + 0x7FFFu + ((u >> 16) & 1u)) >> 16;
    return (ushort)u;
}
__device__ __forceinline__ float b2f_lo(uint u) { return __uint_as_float(u << 16); }
__device__ __forceinline__ float b2f_hi(uint u) { return __uint_as_float(u & 0xFFFF0000u); }

// ---------------- MFMA GEMM: x[nrows,128] fp32 @ W[128,128] fp32 ----------------
// Block 256 = 4 waves; tile 128 rows; wave w owns rows [w*32, w*32+32) (2 m-frags x 8 n-frags).
// W staged once as transposed bf16 Wt[n][k] in LDS, XOR-swizzled to break the
// 16-way bank conflict of column-slice ds_read_b128 (T2). A read direct from global.
__global__ __launch_bounds__(256) void gemm_mfma(const float* __restrict__ x,
                                                 const float* __restrict__ W,
                                                 float* __restrict__ x2f,
                                                 ushort* __restrict__ x2b,
                                                 int nrows) {
    __shared__ ushort Wt[128 * 128];   // 32 KB
    const int tid = threadIdx.x;
    for (int i = tid; i < 4096; i += 256) {
        int k = i >> 5, n0 = (i & 31) * 4;
        float4 w = *(const float4*)(W + k * 128 + n0);
        float wv[4] = {w.x, w.y, w.z, w.w};
#pragma unroll
        for (int j = 0; j < 4; j++) {
            int n = n0 + j;
            Wt[(n * 128 + k) ^ ((n & 7) << 3)] = f2b(wv[j]);
        }
    }
    __syncthreads();

    const int wv_ = tid >> 6;
    const int lane = tid & 63;
    const int ln = lane & 15, kg = lane >> 4;
    const int row_base = blockIdx.x * 128 + wv_ * 32;

    f32x4 acc[2][8];
#pragma unroll
    for (int a = 0; a < 2; a++)
#pragma unroll
        for (int b = 0; b < 8; b++) acc[a][b] = (f32x4)(0.f);

#pragma unroll
    for (int step = 0; step < 4; step++) {
        const int k0 = step * 32 + kg * 8;
        bf16x8 bfr[8];
#pragma unroll
        for (int cf = 0; cf < 8; cf++) {
            int n = cf * 16 + ln;
            bfr[cf] = *(const bf16x8*)&Wt[(n * 128 + k0) ^ ((n & 7) << 3)];
        }
#pragma unroll
        for (int mf = 0; mf < 2; mf++) {
            int row = row_base + mf * 16 + ln;
            bf16x8 afr;
#pragma unroll
            for (int j = 0; j < 8; j++) afr[j] = 0;
            if (row < nrows) {
                const float4* ap = (const float4*)(x + (size_t)row * 128 + k0);
                float4 a0 = ap[0], a1 = ap[1];
                float av[8] = {a0.x, a0.y, a0.z, a0.w, a1.x, a1.y, a1.z, a1.w};
#pragma unroll
                for (int j = 0; j < 8; j++) afr[j] = (short)f2b(av[j]);
            }
#pragma unroll
            for (int cf = 0; cf < 8; cf++)
                acc[mf][cf] = __builtin_amdgcn_mfma_f32_16x16x32_bf16(afr, bfr[cf], acc[mf][cf], 0, 0, 0);
        }
    }

#pragma unroll
    for (int mf = 0; mf < 2; mf++) {
#pragma unroll
        for (int j = 0; j < 4; j++) {
            int row = row_base + mf * 16 + kg * 4 + j;
            if (row >= nrows) continue;
#pragma unroll
            for (int cf = 0; cf < 8; cf++) {
                float v = acc[mf][cf][j];
                int col = cf * 16 + ln;
                x2f[(size_t)row * 128 + col] = v;
                if (x2b) x2b[(size_t)row * 128 + col] = f2b(v);
            }
        }
    }
}

// ---------------- CSR build ----------------
__global__ __launch_bounds__(256) void zero_ints(int* p, int n) {
    int i = blockIdx.x * 256 + threadIdx.x;
    if (i < n) p[i] = 0;
}

__global__ __launch_bounds__(256) void count_deg(const int* __restrict__ ei,
                                                 int* __restrict__ cnt, int ne, int nn) {
    int e = blockIdx.x * 256 + threadIdx.x;
    if (e >= ne) return;
    int dst = ei[e];
    if ((unsigned)dst < (unsigned)nn) atomicAdd(&cnt[dst], 1);
}

__global__ __launch_bounds__(256) void scan_partials(const int* __restrict__ cnt,
                                                     int* __restrict__ bsum, int n) {
    __shared__ int red[256];
    int i = blockIdx.x * 1024 + threadIdx.x * 4;
    int s = 0;
    if (i + 3 < n) {
        int4 v = *(const int4*)(cnt + i);
        s = v.x + v.y + v.z + v.w;
    } else {
        for (int j = i; j < n && j < i + 4; j++) s += cnt[j];
    }
    red[threadIdx.x] = s;
    __syncthreads();
    for (int off = 128; off > 0; off >>= 1) {
        if (threadIdx.x < off) red[threadIdx.x] += red[threadIdx.x + off];
        __syncthreads();
    }
    if (threadIdx.x == 0) bsum[blockIdx.x] = red[0];
}

__global__ __launch_bounds__(1024) void scan_bsums(int* __restrict__ bsum, int nb) {
    __shared__ int s[1024];
    int v = (threadIdx.x < nb) ? bsum[threadIdx.x] : 0;
    s[threadIdx.x] = v;
    __syncthreads();
    for (int off = 1; off < 1024; off <<= 1) {
        int t = (threadIdx.x >= off) ? s[threadIdx.x - off] : 0;
        __syncthreads();
        s[threadIdx.x] += t;
        __syncthreads();
    }
    if (threadIdx.x < nb) bsum[threadIdx.x] = s[threadIdx.x] - v;  // exclusive
}

__global__ __launch_bounds__(256) void scan_apply(const int* __restrict__ cnt,
                                                  const int* __restrict__ bsum,
                                                  int* __restrict__ start,
                                                  int* __restrict__ next, int n) {
    __shared__ int s[256];
    int i = blockIdx.x * 1024 + threadIdx.x * 4;
    int4 v = make_int4(0, 0, 0, 0);
    if (i + 3 < n) {
        v = *(const int4*)(cnt + i);
    } else {
        if (i + 0 < n) v.x = cnt[i + 0];
        if (i + 1 < n) v.y = cnt[i + 1];
        if (i + 2 < n) v.z = cnt[i + 2];
        if (i + 3 < n) v.w = cnt[i + 3];
    }
    int tsum = v.x + v.y + v.z + v.w;
    s[threadIdx.x] = tsum;
    __syncthreads();
    for (int off = 1; off < 256; off <<= 1) {
        int t = (threadIdx.x >= off) ? s[threadIdx.x - off] : 0;
        __syncthreads();
        s[threadIdx.x] += t;
        __syncthreads();
    }
    int r0 = s[threadIdx.x] - tsum + bsum[blockIdx.x];
    int r1 = r0 + v.x, r2 = r1 + v.y, r3 = r2 + v.z;
    if (i + 3 < n) {
        *(int4*)(start + i) = make_int4(r0, r1, r2, r3);
        *(int4*)(next + i) = make_int4(r0, r1, r2, r3);
    } else {
        int rr[4] = {r0, r1, r2, r3};
        for (int j = 0; j < 4 && i + j < n; j++) {
            start[i + j] = rr[j];
            next[i + j] = rr[j];
        }
    }
}

__global__ __launch_bounds__(256) void fill_csr(const int* __restrict__ ei,
                                                int* __restrict__ next,
                                                int* __restrict__ csr, int ne, int nn) {
    int e = blockIdx.x * 256 + threadIdx.x;
    if (e >= ne) return;
    int dst = ei[e];
    int src = ei[ne + e];
    if ((unsigned)dst >= (unsigned)nn || (unsigned)src >= (unsigned)nn) return;
    int slot = atomicAdd(&next[dst], 1);
    csr[slot] = src;
}

// ---------------- gather (bf16 src, fp32 self): one wave per node ----------------
__global__ __launch_bounds__(256) void gather_b16(const int* __restrict__ csr,
                                                  const int* __restrict__ start,
                                                  const int* __restrict__ cnt,
                                                  const uint* __restrict__ x2b,
                                                  const float* __restrict__ x2f,
                                                  float* __restrict__ out, int nn) {
    int wave = (int)((blockIdx.x * 256 + threadIdx.x) >> 6);
    int lane = threadIdx.x & 63;
    if (wave >= nn) return;
    const int s0 = start[wave];
    const int dg = cnt[wave];
    float a0 = 0, a1 = 0, b0 = 0, b1 = 0, c0 = 0, c1 = 0, d0 = 0, d1 = 0;
    int e = 0;
    for (; e + 4 <= dg; e += 4) {
        int s1 = csr[s0 + e], s2 = csr[s0 + e + 1];
        int s3 = csr[s0 + e + 2], s4 = csr[s0 + e + 3];
        uint u1 = x2b[(size_t)s1 * 64 + lane];
        uint u2 = x2b[(size_t)s2 * 64 + lane];
        uint u3 = x2b[(size_t)s3 * 64 + lane];
        uint u4 = x2b[(size_t)s4 * 64 + lane];
        a0 += b2f_lo(u1); a1 += b2f_hi(u1);
        b0 += b2f_lo(u2); b1 += b2f_hi(u2);
        c0 += b2f_lo(u3); c1 += b2f_hi(u3);
        d0 += b2f_lo(u4); d1 += b2f_hi(u4);
    }
    for (; e < dg; e++) {
        int s1 = csr[s0 + e];
        uint u1 = x2b[(size_t)s1 * 64 + lane];
        a0 += b2f_lo(u1); a1 += b2f_hi(u1);
    }
    float2 self = ((const float2*)(x2f + (size_t)wave * 128))[lane];
    float d = (float)dg;
    float2 o;
    o.x = (a0 + b0) + (c0 + d0) - d * self.x;
    o.y = (a1 + b1) + (c1 + d1) - d * self.y;
    ((float2*)out)[(size_t)wave * 64 + lane] = o;
}

// fp32 fallback gather (used only if workspace too small for x2b)
__global__ __launch_bounds__(256) void gather_out(const int* __restrict__ csr,
                                                  const int* __restrict__ start,
                                                  const int* __restrict__ cnt,
                                                  const float* __restrict__ x2,
                                                  float* __restrict__ out, int nn) {
    int wave = (int)((blockIdx.x * 256 + threadIdx.x) >> 6);
    int lane = threadIdx.x & 63;
    if (wave >= nn) return;
    const int s0 = start[wave];
    const int dg = cnt[wave];
    const float2* __restrict__ base = (const float2*)x2;
    float2 acc0 = make_float2(0.f, 0.f), acc1 = make_float2(0.f, 0.f);
    int e = 0;
    for (; e + 2 <= dg; e += 2) {
        int s1 = csr[s0 + e], s2 = csr[s0 + e + 1];
        float2 v1 = base[(size_t)s1 * 64 + lane];
        float2 v2 = base[(size_t)s2 * 64 + lane];
        acc0.x += v1.x; acc0.y += v1.y;
        acc1.x += v2.x; acc1.y += v2.y;
    }
    if (e < dg) {
        int s1 = csr[s0 + e];
        float2 v1 = base[(size_t)s1 * 64 + lane];
        acc0.x += v1.x; acc0.y += v1.y;
    }
    float2 self = base[(size_t)wave * 64 + lane];
    float d = (float)dg;
    float2 o;
    o.x = acc0.x + acc1.x - d * self.x;
    o.y = acc0.y + acc1.y - d * self.y;
    ((float2*)out)[(size_t)wave * 64 + lane] = o;
}

extern "C" void kernel_launch(void* const* d_in, const int* in_sizes, int n_in,
                              void* d_out, int out_size, void* d_ws, size_t ws_size,
                              hipStream_t stream) {
    const float* x = (const float*)d_in[0];
    const int* ei = (const int*)d_in[1];
    const float* W = (const float*)d_in[2];
    // d_in[3] (bias) provably unused: cancels in out = A@x2 - x2*deg.
    float* out = (float*)d_out;

    const int n = in_sizes[0] / C_DIM;     // 100000
    const int ne = in_sizes[1] / 2;        // 1600000
    const int nb = (n + 1023) / 1024;      // scan tiles (<=1024)

    const size_t sz_x2f = (size_t)n * C_DIM * sizeof(float);
    const size_t sz_x2b = (size_t)n * C_DIM * sizeof(ushort);
    const size_t sz_int = (size_t)n * sizeof(int);
    const size_t sz_bs = (size_t)((nb + 3) & ~3) * sizeof(int);
    const size_t need_b16 = sz_x2f + sz_x2b + 3 * sz_int + sz_bs + (size_t)ne * sizeof(int);
    const bool use_b16 = ws_size >= need_b16;

    char* ws = (char*)d_ws;
    float* x2f = (float*)ws;                ws += sz_x2f;
    ushort* x2b = nullptr;
    if (use_b16) { x2b = (ushort*)ws;       ws += sz_x2b; }
    int* cnt = (int*)ws;                    ws += sz_int;
    int* start = (int*)ws;                  ws += sz_int;
    int* next = (int*)ws;                   ws += sz_int;
    int* bsum = (int*)ws;                   ws += sz_bs;
    int* csr = (int*)ws;

    zero_ints<<<(n + 255) / 256, 256, 0, stream>>>(cnt, n);

    int ntiles = (n + 127) / 128;
    gemm_mfma<<<ntiles, 256, 0, stream>>>(x, W, x2f, x2b, n);

    int eblocks = (ne + 255) / 256;
    count_deg<<<eblocks, 256, 0, stream>>>(ei, cnt, ne, n);

    scan_partials<<<nb, 256, 0, stream>>>(cnt, bsum, n);
    scan_bsums<<<1, 1024, 0, stream>>>(bsum, nb);
    scan_apply<<<nb, 256, 0, stream>>>(cnt, bsum, start, next, n);

    fill_csr<<<eblocks, 256, 0, stream>>>(ei, next, csr, ne, n);

    int gblocks = (n + 3) / 4;   // 4 waves per block, 1 node per wave
    if (use_b16)
        gather_b16<<<gblocks, 256, 0, stream>>>(csr, start, cnt, (const uint*)x2b, x2f, out, n);
    else
        gather_out<<<gblocks, 256, 0, stream>>>(csr, start, cnt, x2f, out, n);
}